// Round 14
// baseline (1347.826 us; speedup 1.0000x reference)
//
#include <hip/hip_runtime.h>

// PACE DAG-transformer encoder, MI355X bf16-MFMA implementation. Round 14:
// 8-phase 256^2/BK=64 schedule ported to gemm_qkv (guide's m201 template,
// adapted): 8 waves of 128x64 (acc[8][4], (512,2) - no r11 spill), 128KB
// LDS [2buf][2half][128][64], 16B-granule XOR swizzle, 4 quadrant-phases
// per K-tile with counted vmcnt(2) + 2 barriers per K=64 (vs full drain +
// 2 barriers per K=32 in r13). LDS-read/FLOP 0.75x, drain frequency 0.5x.
// Everything else r13-exact (control).

typedef unsigned short u16;
typedef unsigned int u32;
typedef __attribute__((ext_vector_type(8))) short bf16x8;
typedef __attribute__((ext_vector_type(4))) float f32x4;

#define NB 1024
#define MAXN 32
#define NHID 512
#define NHEAD 8
#define NLAY 6
#define MTOT (NB * MAXN)   // 32768 rows
#define ATT_SCALE 0.125f
#define LN_EPS 1e-5f

__device__ __forceinline__ float bf2f(u16 h) { return __uint_as_float(((u32)h) << 16); }
__device__ __forceinline__ u16 f2bf(float f) {
  u32 u = __float_as_uint(f);
  return (u16)((u + 0x7fffu + ((u >> 16) & 1u)) >> 16);
}

__device__ __forceinline__ void gload16(const void* g, void* l) {
  __builtin_amdgcn_global_load_lds((const __attribute__((address_space(1))) void*)g,
                                   (__attribute__((address_space(3))) void*)l, 16, 0, 0);
}

// XCD-aware remap: all NX n-blocks of one m-panel on one XCD.
__device__ __forceinline__ void xcd_remap(int l, int NX, int& mt, int& nt) {
  int xcd = l & 7;
  int s = l >> 3;
  int mg = s / NX;
  nt = s - mg * NX;
  mt = mg * 8 + xcd;
}

// ---------------------------------------------------------------------------
// DAG reachability mask: per (b,q) a 32-bit "allowed key" mask.
__global__ __launch_bounds__(256) void mask_k(const int* __restrict__ adj, u32* __restrict__ mask) {
  __shared__ u32 r[8][32];
  int tid = threadIdx.x;
  int g = tid >> 5, i = tid & 31;
  int b = blockIdx.x * 8 + g;
  const int* ab = adj + ((long)b * 32 + i) * 32;
  u32 m = 0;
  for (int j = i + 1; j < 32; ++j)
    if (ab[j]) m |= (1u << j);
  r[g][i] = m;
  __syncthreads();
  for (int it = 0; it < 5; ++it) {
    u32 cur = r[g][i];
    u32 acc = cur;
    #pragma unroll
    for (int j = 0; j < 32; ++j)
      if ((cur >> j) & 1u) acc |= r[g][j];
    __syncthreads();
    r[g][i] = acc;
    __syncthreads();
  }
  u32 am = 1u << i;
  #pragma unroll
  for (int k = 0; k < 32; ++k) am |= ((r[g][k] >> i) & 1u) << k;
  mask[b * 32 + i] = am;
}

// ---------------------------------------------------------------------------
// Embedding -> xb (bf16 only).
__global__ __launch_bounds__(256) void embed_k(const int* __restrict__ types,
    const float* __restrict__ Wpos, const float* __restrict__ bpos,
    const float* __restrict__ Wnode, const float* __restrict__ bnode,
    u16* __restrict__ xb) {
  int i = blockIdx.x * 256 + threadIdx.x;
  int row = i >> 7, c = (i & 127) * 4;
  int b = row >> 5, n = row & 31;
  float v[4];
  if (c < 256) {
    int tp = types[b * 32 + n];
    const float* w = &Wnode[tp * 256 + c];
    #pragma unroll
    for (int j = 0; j < 4; ++j) v[j] = fmaxf(w[j] + bnode[c + j], 0.f);
  } else {
    int cc = c - 256;
    const float* w = &Wpos[n * 256 + cc];
    #pragma unroll
    for (int j = 0; j < 4; ++j) v[j] = w[j] + bpos[cc + j];
  }
  ushort4 h; h.x = f2bf(v[0]); h.y = f2bf(v[1]); h.z = f2bf(v[2]); h.w = f2bf(v[3]);
  *(ushort4*)&xb[(long)row * NHID + c] = h;
}

// ---------------------------------------------------------------------------
// Weight transpose + f32->bf16: W[l][k][n] -> Wt[l][n_off+n][k]
__global__ __launch_bounds__(256) void tconv_k(const float* __restrict__ W,
    u16* __restrict__ Wt, int n_off, int n_total) {
  __shared__ float tile[32][33];
  int l = blockIdx.z;
  int k0 = blockIdx.x * 32, n0 = blockIdx.y * 32;
  int tx = threadIdx.x & 31, ty = threadIdx.x >> 5;
  const float* src = W + (size_t)l * NHID * NHID;
  #pragma unroll
  for (int i = 0; i < 4; ++i)
    tile[ty + 8 * i][tx] = src[(size_t)(k0 + ty + 8 * i) * NHID + n0 + tx];
  __syncthreads();
  u16* dst = Wt + (size_t)l * n_total * NHID;
  #pragma unroll
  for (int i = 0; i < 4; ++i)
    dst[(size_t)(n_off + n0 + ty + 8 * i) * NHID + k0 + tx] = f2bf(tile[tx][ty + 8 * i]);
}

// ---------------------------------------------------------------------------
// QKV GEMM, 8-phase schedule: 256x256 tile, BK=64, 8 waves (2M x 4N) of
// 128x64, 128KB LDS, counted vmcnt(2), 2 barriers per K-tile.
__global__ __launch_bounds__(512, 2) void gemm_qkv(
    const u16* __restrict__ A, const u16* __restrict__ Bt,
    const float* __restrict__ bq, const float* __restrict__ bk,
    const float* __restrict__ bv, u16* __restrict__ qk, u16* __restrict__ v) {
  __shared__ u16 Al[2][2][128 * 64];   // [buf][half][row*64 + gran*8]  64 KB
  __shared__ u16 Bl[2][2][128 * 64];   // 64 KB
  const int tid = threadIdx.x;
  const int lane = tid & 63;
  const int wave = tid >> 6;
  int mt, nt_;
  xcd_remap(blockIdx.x + gridDim.x * blockIdx.y, gridDim.x, mt, nt_);
  const long m0 = (long)mt * 256;
  const int n0 = nt_ * 256;
  const int wr = wave >> 2;            // 0..1 : 128-row half
  const int wcn = wave & 3;            // 0..3 : 64-col quarter
  const int fr = lane & 15, kq = lane >> 4;
  const int sr = tid >> 3, sp = tid & 7;    // stage row (0..63), granule pos
  const int sgg = sp ^ (sr & 7);            // pre-swizzled global granule
  f32x4 acc[8][4] = {};

  // stage one half-tile (128 rows x 64 k): hsel 0,1 = A halves; 2,3 = B halves
  auto stageH = [&](int kt, int hsel) {
    int buf = kt & 1;
    int kof = kt * 64 + sgg * 8;
    if (hsel < 2) {
      const u16* src = A + (m0 + hsel * 128 + sr) * 512L + kof;
      u16* dst = &Al[buf][hsel][sr * 64 + sp * 8];
      gload16(src, dst);
      gload16(src + 64 * 512L, dst + 64 * 64);
    } else {
      const u16* src = Bt + (long)(n0 + (hsel - 2) * 128 + sr) * 512 + kof;
      u16* dst = &Bl[buf][hsel - 2][sr * 64 + sp * 8];
      gload16(src, dst);
      gload16(src + 64 * 512L, dst + 64 * 64);
    }
  };
  stageH(0, 0); stageH(0, 1); stageH(0, 2); stageH(0, 3);

  #pragma unroll 1
  for (int kt = 0; kt < 8; ++kt) {
    const int buf = kt & 1;
    const u16* Ah = &Al[buf][wr][0];
    #pragma unroll
    for (int ph = 0; ph < 4; ++ph) {
      if (kt < 7) stageH(kt + 1, ph);          // A h0, A h1, B h0, B h1
      if (ph == 0) {
        if (kt < 7) asm volatile("s_waitcnt vmcnt(2)" ::: "memory");
        else        asm volatile("s_waitcnt vmcnt(0)" ::: "memory");
        __builtin_amdgcn_s_barrier();          // kt's 4 halves visible to all
      }
      const int mih = ph >> 1, nih = ph & 1;   // quadrant: 64 rows x 32 cols
      bf16x8 af[4][2], bfv[2][2];
      #pragma unroll
      for (int kh = 0; kh < 2; ++kh) {
        #pragma unroll
        for (int m2 = 0; m2 < 4; ++m2) {
          int r = mih * 64 + m2 * 16 + fr;
          int p = (kh * 4 + kq) ^ (r & 7);
          af[m2][kh] = *(const bf16x8*)&Ah[r * 64 + p * 8];
        }
        #pragma unroll
        for (int n2 = 0; n2 < 2; ++n2) {
          int c = wcn * 64 + nih * 32 + n2 * 16 + fr;
          int p = (kh * 4 + kq) ^ (c & 7);
          bfv[n2][kh] = *(const bf16x8*)&Bl[buf][c >> 7][(c & 127) * 64 + p * 8];
        }
      }
      __builtin_amdgcn_s_setprio(1);
      #pragma unroll
      for (int kh = 0; kh < 2; ++kh)
        #pragma unroll
        for (int m2 = 0; m2 < 4; ++m2)
          #pragma unroll
          for (int n2 = 0; n2 < 2; ++n2)
            acc[mih * 4 + m2][nih * 2 + n2] = __builtin_amdgcn_mfma_f32_16x16x32_bf16(
                bfv[n2][kh], af[m2][kh], acc[mih * 4 + m2][nih * 2 + n2], 0, 0, 0);
      __builtin_amdgcn_s_setprio(0);
      if (ph == 3) __builtin_amdgcn_s_barrier();   // buf reads done before next kt stages
    }
  }

  #pragma unroll
  for (int mi = 0; mi < 8; ++mi) {
    long r = m0 + wr * 128 + mi * 16 + fr;
    #pragma unroll
    for (int ni = 0; ni < 4; ++ni) {
      int n = n0 + wcn * 64 + ni * 16 + kq * 4;
      const float* bp = (n < 512) ? bq : ((n < 1024) ? bk : bv);
      float4 bvv = *(const float4*)&bp[n & 511];
      ushort4 st;
      st.x = f2bf(acc[mi][ni][0] + bvv.x);
      st.y = f2bf(acc[mi][ni][1] + bvv.y);
      st.z = f2bf(acc[mi][ni][2] + bvv.z);
      st.w = f2bf(acc[mi][ni][3] + bvv.w);
      if (n < 1024) *(ushort4*)&qk[r * 1024 + n] = st;
      else          *(ushort4*)&v[r * 512 + (n - 1024)] = st;
    }
  }
}

// ---------------------------------------------------------------------------
// W1 GEMM (bias+relu): 128x128 tile, 2-slot, 4 blocks/CU, setprio. (r13-exact)
__global__ __launch_bounds__(256, 4) void gemm_relu(
    const u16* __restrict__ A, const u16* __restrict__ Bt,
    const float* __restrict__ bias0, u16* __restrict__ Cout) {
  __shared__ u16 As[2][128 * 32];
  __shared__ u16 Bs[2][128 * 32];
  const int tid = threadIdx.x;
  const int wave = tid >> 6, lane = tid & 63;
  int mt, nt_;
  xcd_remap(blockIdx.x + gridDim.x * blockIdx.y, gridDim.x, mt, nt_);
  const long m0 = (long)mt * 128;
  const int n0 = nt_ * 128;
  const int wr = wave >> 1, wc = wave & 1;
  const int srow = lane >> 2;
  const int sg = (lane & 3) ^ ((srow >> 1) & 3);
  const int fr = lane & 15;
  const int kq = lane >> 4;
  f32x4 acc[4][4] = {};

  auto stage = [&](int buf, int k0) {
    #pragma unroll
    for (int i = 0; i < 2; ++i) {
      int c = 2 * wave + i;
      gload16(A + (m0 + 16 * c + srow) * 512L + k0 + sg * 8, &As[buf][c * 512]);
      gload16(Bt + (long)(n0 + 16 * c + srow) * 512 + k0 + sg * 8, &Bs[buf][c * 512]);
    }
  };
  stage(0, 0);
  const int kqx = (kq ^ ((fr >> 1) & 3)) * 8;
  #pragma unroll 1
  for (int t = 0; t < 16; ++t) {
    asm volatile("s_waitcnt vmcnt(0)" ::: "memory");
    __builtin_amdgcn_s_barrier();
    if (t + 1 < 16) stage((t + 1) & 1, (t + 1) * 32);
    const u16* Asl = As[t & 1];
    const u16* Bsl = Bs[t & 1];
    __builtin_amdgcn_s_setprio(1);
    bf16x8 af[4], bfv[4];
    #pragma unroll
    for (int mi = 0; mi < 4; ++mi)
      af[mi] = *(const bf16x8*)&Asl[(wr * 64 + mi * 16 + fr) * 32 + kqx];
    #pragma unroll
    for (int ni = 0; ni < 4; ++ni)
      bfv[ni] = *(const bf16x8*)&Bsl[(wc * 64 + ni * 16 + fr) * 32 + kqx];
    #pragma unroll
    for (int mi = 0; mi < 4; ++mi)
      #pragma unroll
      for (int ni = 0; ni < 4; ++ni)
        acc[mi][ni] = __builtin_amdgcn_mfma_f32_16x16x32_bf16(bfv[ni], af[mi], acc[mi][ni], 0, 0, 0);
    __builtin_amdgcn_s_setprio(0);
  }

  #pragma unroll
  for (int mi = 0; mi < 4; ++mi) {
    long r = m0 + wr * 64 + mi * 16 + fr;
    #pragma unroll
    for (int ni = 0; ni < 4; ++ni) {
      int n = n0 + wc * 64 + ni * 16 + kq * 4;
      float4 bvv = *(const float4*)&bias0[n];
      ushort4 st;
      st.x = f2bf(fmaxf(acc[mi][ni][0] + bvv.x, 0.f));
      st.y = f2bf(fmaxf(acc[mi][ni][1] + bvv.y, 0.f));
      st.z = f2bf(fmaxf(acc[mi][ni][2] + bvv.z, 0.f));
      st.w = f2bf(fmaxf(acc[mi][ni][3] + bvv.w, 0.f));
      *(ushort4*)&Cout[r * 512 + n] = st;
    }
  }
}

// ---------------------------------------------------------------------------
// GEMM + residual + LayerNorm: 128x512 block, 8 waves of 64x128, 2-slot 80KB,
// (512,2). (r13-exact)
__global__ __launch_bounds__(512, 2) void gemm_ln(
    const u16* __restrict__ A, const u16* __restrict__ Bt,
    const float* __restrict__ bias0, const float* __restrict__ g,
    const float* __restrict__ b, u16* __restrict__ xb) {
  __shared__ u16 As[2][128 * 32];
  __shared__ u16 Bs[2][512 * 32];
  const int tid = threadIdx.x;
  const int wave = tid >> 6, lane = tid & 63;
  const long m0 = (long)blockIdx.x * 128;
  const int wr = wave >> 2, wc = wave & 3;
  const int srow = lane >> 2;
  const int sg = (lane & 3) ^ ((srow >> 1) & 3);
  const int fr = lane & 15;
  const int kq = lane >> 4;
  f32x4 acc[4][8] = {};

  auto stage = [&](int buf, int k0) {
    gload16(A + (m0 + 16 * wave + srow) * 512L + k0 + sg * 8, &As[buf][wave * 512]);
    #pragma unroll
    for (int i = 0; i < 4; ++i) {
      int c = 4 * wave + i;
      gload16(Bt + (long)(16 * c + srow) * 512 + k0 + sg * 8, &Bs[buf][c * 512]);
    }
  };
  stage(0, 0);
  const int kqx = (kq ^ ((fr >> 1) & 3)) * 8;
  #pragma unroll 1
  for (int t = 0; t < 16; ++t) {
    asm volatile("s_waitcnt vmcnt(0)" ::: "memory");
    __builtin_amdgcn_s_barrier();
    if (t + 1 < 16) stage((t + 1) & 1, (t + 1) * 32);
    const u16* Asl = As[t & 1];
    const u16* Bsl = Bs[t & 1];
    __builtin_amdgcn_s_setprio(1);
    bf16x8 af[4], bfv[8];
    #pragma unroll
    for (int mi = 0; mi < 4; ++mi)
      af[mi] = *(const bf16x8*)&Asl[(wr * 64 + mi * 16 + fr) * 32 + kqx];
    #pragma unroll
    for (int ni = 0; ni < 8; ++ni)
      bfv[ni] = *(const bf16x8*)&Bsl[(wc * 128 + ni * 16 + fr) * 32 + kqx];
    #pragma unroll
    for (int mi = 0; mi < 4; ++mi)
      #pragma unroll
      for (int ni = 0; ni < 8; ++ni)
        acc[mi][ni] = __builtin_amdgcn_mfma_f32_16x16x32_bf16(bfv[ni], af[mi], acc[mi][ni], 0, 0, 0);
    __builtin_amdgcn_s_setprio(0);
  }

  float s[4], sq[4];
  #pragma unroll
  for (int mi = 0; mi < 4; ++mi) {
    long r = m0 + wr * 64 + mi * 16 + fr;
    float ss = 0.f, qq = 0.f;
    #pragma unroll
    for (int ni = 0; ni < 8; ++ni) {
      int n = wc * 128 + ni * 16 + kq * 4;
      float4 bvv = *(const float4*)&bias0[n];
      ushort4 rv = *(const ushort4*)&xb[r * 512 + n];
      float y0 = acc[mi][ni][0] + bvv.x + bf2f(rv.x);
      float y1 = acc[mi][ni][1] + bvv.y + bf2f(rv.y);
      float y2 = acc[mi][ni][2] + bvv.z + bf2f(rv.z);
      float y3 = acc[mi][ni][3] + bvv.w + bf2f(rv.w);
      acc[mi][ni][0] = y0; acc[mi][ni][1] = y1;
      acc[mi][ni][2] = y2; acc[mi][ni][3] = y3;
      ss += y0 + y1 + y2 + y3;
      qq += y0 * y0 + y1 * y1 + y2 * y2 + y3 * y3;
    }
    s[mi] = ss; sq[mi] = qq;
  }
  #pragma unroll
  for (int mi = 0; mi < 4; ++mi) {
    s[mi] += __shfl_xor(s[mi], 16);  sq[mi] += __shfl_xor(sq[mi], 16);
    s[mi] += __shfl_xor(s[mi], 32);  sq[mi] += __shfl_xor(sq[mi], 32);
  }
  __syncthreads();
  float* red = (float*)&As[0][0];
  if (lane < 16) {
    #pragma unroll
    for (int mi = 0; mi < 4; ++mi) {
      int idx = ((wr * 64 + mi * 16 + fr) * 4 + wc) * 2;
      red[idx] = s[mi];
      red[idx + 1] = sq[mi];
    }
  }
  __syncthreads();
  #pragma unroll
  for (int mi = 0; mi < 4; ++mi) {
    int rl = wr * 64 + mi * 16 + fr;
    float S = red[(rl * 4 + 0) * 2] + red[(rl * 4 + 1) * 2] + red[(rl * 4 + 2) * 2] + red[(rl * 4 + 3) * 2];
    float Q = red[(rl * 4 + 0) * 2 + 1] + red[(rl * 4 + 1) * 2 + 1] + red[(rl * 4 + 2) * 2 + 1] + red[(rl * 4 + 3) * 2 + 1];
    float mean = S * (1.f / 512.f);
    float inv = rsqrtf(Q * (1.f / 512.f) - mean * mean + LN_EPS);
    long r = m0 + rl;
    #pragma unroll
    for (int ni = 0; ni < 8; ++ni) {
      int n = wc * 128 + ni * 16 + kq * 4;
      float4 g4 = *(const float4*)&g[n];
      float4 b4 = *(const float4*)&b[n];
      ushort4 st;
      st.x = f2bf((acc[mi][ni][0] - mean) * inv * g4.x + b4.x);
      st.y = f2bf((acc[mi][ni][1] - mean) * inv * g4.y + b4.y);
      st.z = f2bf((acc[mi][ni][2] - mean) * inv * g4.z + b4.z);
      st.w = f2bf((acc[mi][ni][3] - mean) * inv * g4.w + b4.w);
      *(ushort4*)&xb[r * 512 + n] = st;
    }
  }
}

// ---------------------------------------------------------------------------
// MFMA attention: 1 wave per (b,head), 4 waves/block, no barriers. (r13-exact)
__global__ __launch_bounds__(256) void attn_k(const u16* __restrict__ qk,
    const u16* __restrict__ vfull, const u32* __restrict__ mask, u16* __restrict__ o) {
  __shared__ u16 vs_[4][64][40];
  __shared__ u16 p_lds[4][32][40];
  int tid = threadIdx.x;
  int w = tid >> 6, lane = tid & 63;
  int idx = blockIdx.x * 4 + w;
  int b = idx >> 3, h = idx & 7;
  const u16* qbase = qk + (long)b * 32 * 1024 + h * 64;
  const u16* kbase = qbase + 512;
  int g = lane >> 4, r = lane & 15;

  int node = lane >> 1, dh = lane & 1;
  const u16* vsrc = vfull + ((long)b * 32 + node) * 512 + h * 64 + dh * 32;
  bf16x8 vr[4];
  #pragma unroll
  for (int i = 0; i < 4; ++i) vr[i] = *(const bf16x8*)(vsrc + i * 8);

  f32x4 s[2][2] = {};
  #pragma unroll
  for (int ks = 0; ks < 2; ++ks) {
    bf16x8 kf[2], qf[2];
    #pragma unroll
    for (int mi = 0; mi < 2; ++mi)
      kf[mi] = *(const bf16x8*)(kbase + (long)(mi * 16 + r) * 1024 + ks * 32 + g * 8);
    #pragma unroll
    for (int nj = 0; nj < 2; ++nj)
      qf[nj] = *(const bf16x8*)(qbase + (long)(nj * 16 + r) * 1024 + ks * 32 + g * 8);
    #pragma unroll
    for (int mi = 0; mi < 2; ++mi)
      #pragma unroll
      for (int nj = 0; nj < 2; ++nj)
        s[mi][nj] = __builtin_amdgcn_mfma_f32_16x16x32_bf16(kf[mi], qf[nj], s[mi][nj], 0, 0, 0);
  }

  #pragma unroll
  for (int i = 0; i < 4; ++i)
    #pragma unroll
    for (int t = 0; t < 8; ++t)
      vs_[w][dh * 32 + i * 8 + t][node] = (u16)vr[i][t];

  #pragma unroll
  for (int nj = 0; nj < 2; ++nj) {
    int q = nj * 16 + r;
    u32 mk = mask[b * 32 + q];
    float vv[8];
    float mx = -1e30f;
    #pragma unroll
    for (int mi = 0; mi < 2; ++mi)
      #pragma unroll
      for (int j = 0; j < 4; ++j) {
        int k = mi * 16 + g * 4 + j;
        float val = ((mk >> k) & 1u) ? s[mi][nj][j] * ATT_SCALE : -1e30f;
        vv[mi * 4 + j] = val;
        mx = fmaxf(mx, val);
      }
    mx = fmaxf(mx, __shfl_xor(mx, 16));
    mx = fmaxf(mx, __shfl_xor(mx, 32));
    float sum = 0.f;
    #pragma unroll
    for (int i = 0; i < 8; ++i) { vv[i] = __expf(vv[i] - mx); sum += vv[i]; }
    sum += __shfl_xor(sum, 16);
    sum += __shfl_xor(sum, 32);
    float inv = 1.f / sum;
    #pragma unroll
    for (int mi = 0; mi < 2; ++mi) {
      ushort4 pk;
      pk.x = f2bf(vv[mi * 4 + 0] * inv);
      pk.y = f2bf(vv[mi * 4 + 1] * inv);
      pk.z = f2bf(vv[mi * 4 + 2] * inv);
      pk.w = f2bf(vv[mi * 4 + 3] * inv);
      *(ushort4*)&p_lds[w][q][mi * 16 + g * 4] = pk;
    }
  }

  bf16x8 pa[2];
  #pragma unroll
  for (int mi = 0; mi < 2; ++mi)
    pa[mi] = *(const bf16x8*)&p_lds[w][mi * 16 + r][g * 8];
  f32x4 oacc[2][4] = {};
  #pragma unroll
  for (int nd = 0; nd < 4; ++nd) {
    bf16x8 vf = *(const bf16x8*)&vs_[w][nd * 16 + r][g * 8];
    #pragma unroll
    for (int mi = 0; mi < 2; ++mi)
      oacc[mi][nd] = __builtin_amdgcn_mfma_f32_16x16x32_bf16(pa[mi], vf, oacc[mi][nd], 0, 0, 0);
  }
  #pragma unroll
  for (int mi = 0; mi < 2; ++mi)
    #pragma unroll
    for (int j = 0; j < 4; ++j) {
      int q = mi * 16 + g * 4 + j;
      u16* og = o + ((long)b * 32 + q) * NHID + h * 64;
      #pragma unroll
      for (int nd = 0; nd < 4; ++nd)
        og[nd * 16 + r] = f2bf(oacc[mi][nd][j]);
    }
}

// ---------------------------------------------------------------------------
// Final FC weight transpose: W[16384][64] f32 -> Wt[sel*64 + n][16384] bf16.
__global__ __launch_bounds__(256) void fcT_k(const float* __restrict__ W1,
    const float* __restrict__ W2, u16* __restrict__ Wt) {
  __shared__ float t[64][65];
  int sel = blockIdx.y;
  const float* W = sel ? W2 : W1;
  int k0 = blockIdx.x * 64;
  int tx = threadIdx.x & 63, ty = threadIdx.x >> 6;
  #pragma unroll
  for (int i = 0; i < 16; ++i)
    t[ty + 4 * i][tx] = W[(long)(k0 + ty + 4 * i) * 64 + tx];
  __syncthreads();
  #pragma unroll
  for (int i = 0; i < 16; ++i)
    Wt[(long)(sel * 64 + ty + 4 * i) * 16384 + k0 + tx] = f2bf(t[tx][ty + 4 * i]);
}

// ---------------------------------------------------------------------------
// Final FC GEMM (2-slot, swapped-operand), K-split: part[ks][1024][128].
__global__ __launch_bounds__(256, 4) void gemm_fc(const u16* __restrict__ A,
    const u16* __restrict__ Bt, float* __restrict__ part) {
  __shared__ u16 As[2][128 * 32];
  __shared__ u16 Bs[2][128 * 32];
  const int tid = threadIdx.x;
  const int wave = tid >> 6, lane = tid & 63;
  const int ks = blockIdx.x;
  const long m0 = (long)blockIdx.y * 128;
  const int kbase = ks * 512;
  const int wr = wave >> 1, wc = wave & 1;
  const int srow = lane >> 2;
  const int sg = (lane & 3) ^ ((srow >> 1) & 3);
  const int fr = lane & 15;
  const int kq = lane >> 4;
  f32x4 acc[4][4] = {};
  auto stage = [&](int buf, int k0) {
    #pragma unroll
    for (int i = 0; i < 2; ++i) {
      int c = 2 * wave + i;
      gload16(A + (m0 + 16 * c + srow) * 16384L + kbase + k0 + sg * 8, &As[buf][c * 512]);
      gload16(Bt + (long)(16 * c + srow) * 16384L + kbase + k0 + sg * 8, &Bs[buf][c * 512]);
    }
  };
  stage(0, 0);
  const int kqx = (kq ^ ((fr >> 1) & 3)) * 8;
  #pragma unroll 1
  for (int t = 0; t < 16; ++t) {
    asm volatile("s_waitcnt vmcnt(0)" ::: "memory");
    __builtin_amdgcn_s_barrier();
    if (t + 1 < 16) stage((t + 1) & 1, (t + 1) * 32);
    const u16* Asl = As[t & 1];
    const u16* Bsl = Bs[t & 1];
    __builtin_amdgcn_s_setprio(1);
    bf16x8 af[4], bfv[4];
    #pragma unroll
    for (int mi = 0; mi < 4; ++mi)
      af[mi] = *(const bf16x8*)&Asl[(wr * 64 + mi * 16 + fr) * 32 + kqx];
    #pragma unroll
    for (int ni = 0; ni < 4; ++ni)
      bfv[ni] = *(const bf16x8*)&Bsl[(wc * 64 + ni * 16 + fr) * 32 + kqx];
    #pragma unroll
    for (int mi = 0; mi < 4; ++mi)
      #pragma unroll
      for (int ni = 0; ni < 4; ++ni)
        acc[mi][ni] = __builtin_amdgcn_mfma_f32_16x16x32_bf16(bfv[ni], af[mi], acc[mi][ni], 0, 0, 0);
    __builtin_amdgcn_s_setprio(0);
  }
  #pragma unroll
  for (int mi = 0; mi < 4; ++mi) {
    long rr = m0 + wr * 64 + mi * 16 + fr;
    #pragma unroll
    for (int ni = 0; ni < 4; ++ni) {
      int n = wc * 64 + ni * 16 + kq * 4;
      *(float4*)&part[((long)ks * 1024 + rr) * 128 + n] =
          make_float4(acc[mi][ni][0], acc[mi][ni][1], acc[mi][ni][2], acc[mi][ni][3]);
    }
  }
}

__global__ __launch_bounds__(256) void fc_red_k(const float* __restrict__ part,
    const float* __restrict__ bfc1, const float* __restrict__ bfc2,
    float* __restrict__ out) {
  int idx = blockIdx.x * 256 + threadIdx.x;
  int sel = idx >> 16;
  int rem = idx & 65535;
  int b = rem >> 6, z = rem & 63;
  float v = sel ? bfc2[z] : bfc1[z];
  #pragma unroll
  for (int ks = 0; ks < 32; ++ks)
    v += part[((long)ks * 1024 + b) * 128 + sel * 64 + z];
  out[idx] = v;
}

// ---------------------------------------------------------------------------
extern "C" void kernel_launch(void* const* d_in, const int* in_sizes, int n_in,
                              void* d_out, int out_size, void* d_ws, size_t ws_size,
                              hipStream_t stream) {
  const int* node_types = (const int*)d_in[0];
  const int* adj_bits = (const int*)d_in[1];
  const float* Wpos = (const float*)d_in[2];
  const float* bpos = (const float*)d_in[3];
  const float* Wnode = (const float*)d_in[4];
  const float* bnode = (const float*)d_in[5];
  const float* eWq = (const float*)d_in[6];
  const float* eWk = (const float*)d_in[7];
  const float* eWv = (const float*)d_in[8];
  const float* eWo = (const float*)d_in[9];
  const float* eW1 = (const float*)d_in[10];
  const float* eW2 = (const float*)d_in[11];
  const float* ebq = (const float*)d_in[12];
  const float* ebk = (const float*)d_in[13];
  const float* ebv = (const float*)d_in[14];
  const float* ebo = (const float*)d_in[15];
  const float* eb1 = (const float*)d_in[16];
  const float* eb2 = (const float*)d_in[17];
  const float* ln1g = (const float*)d_in[18];
  const float* ln1b = (const float*)d_in[19];
  const float* ln2g = (const float*)d_in[20];
  const float* ln2b = (const float*)d_in[21];
  const float* Wfc1 = (const float*)d_in[22];
  const float* bfc1 = (const float*)d_in[23];
  const float* Wfc2 = (const float*)d_in[24];
  const float* bfc2 = (const float*)d_in[25];

  char* ws = (char*)d_ws;
  size_t off = 0;
  auto carve = [&](size_t bytes) {
    void* p = ws + off;
    off += (bytes + 255) & ~(size_t)255;
    return p;
  };
  u16* Wqkv_t = (u16*)carve((size_t)NLAY * 1536 * 512 * 2);
  u16* Wo_t = (u16*)carve((size_t)NLAY * 512 * 512 * 2);
  u16* W1_t = (u16*)carve((size_t)NLAY * 512 * 512 * 2);
  u16* W2_t = (u16*)carve((size_t)NLAY * 512 * 512 * 2);
  u16* xb = (u16*)carve((size_t)MTOT * NHID * 2);       // 32 MB: layer state
  u16* qk = (u16*)carve((size_t)MTOT * 1024 * 2);       // 64 MB: Q,K / Wt_fc
  u16* vbuf = (u16*)carve((size_t)MTOT * NHID * 2);     // 32 MB: V packed
  u16* obuf = (u16*)carve((size_t)MTOT * NHID * 2);     // 32 MB: attn out / hbuf / part
  u32* maskb = (u32*)carve((size_t)NB * MAXN * 4);
  u16* hbuf = obuf;               // MLP hidden
  u16* Wt_fc = qk;                // FC-time alias: 4 MB
  float* part_fc = (float*)obuf;  // FC-time alias: 16.8 MB

  // --- prep ---
  mask_k<<<NB / 8, 256, 0, stream>>>(adj_bits, maskb);
  embed_k<<<(MTOT * 128) / 256, 256, 0, stream>>>(node_types, Wpos, bpos, Wnode, bnode, xb);
  dim3 tg(16, 16, NLAY);
  tconv_k<<<tg, 256, 0, stream>>>(eWq, Wqkv_t, 0, 1536);
  tconv_k<<<tg, 256, 0, stream>>>(eWk, Wqkv_t, 512, 1536);
  tconv_k<<<tg, 256, 0, stream>>>(eWv, Wqkv_t, 1024, 1536);
  tconv_k<<<tg, 256, 0, stream>>>(eWo, Wo_t, 0, 512);
  tconv_k<<<tg, 256, 0, stream>>>(eW1, W1_t, 0, 512);
  tconv_k<<<tg, 256, 0, stream>>>(eW2, W2_t, 0, 512);

  // --- encoder layers ---
  for (int l = 0; l < NLAY; ++l) {
    size_t lw = (size_t)l * 512 * 512;
    gemm_qkv<<<dim3(6, MTOT / 256), 512, 0, stream>>>(
        xb, Wqkv_t + (size_t)l * 1536 * 512,
        ebq + l * 512, ebk + l * 512, ebv + l * 512, qk, vbuf);
    attn_k<<<NB * NHEAD / 4, 256, 0, stream>>>(qk, vbuf, maskb, obuf);
    gemm_ln<<<MTOT / 128, 512, 0, stream>>>(
        obuf, Wo_t + lw, ebo + l * 512, ln1g + l * 512, ln1b + l * 512, xb);
    gemm_relu<<<dim3(4, MTOT / 128), 256, 0, stream>>>(
        xb, W1_t + lw, eb1 + l * 512, hbuf);
    gemm_ln<<<MTOT / 128, 512, 0, stream>>>(
        hbuf, W2_t + lw, eb2 + l * 512, ln2g + l * 512, ln2b + l * 512, xb);
  }

  // --- final FC: transpose weights (dead qk region), K-split MFMA, reduce ---
  fcT_k<<<dim3(256, 2), 256, 0, stream>>>(Wfc1, Wfc2, Wt_fc);
  gemm_fc<<<dim3(32, 8), 256, 0, stream>>>(xb, Wt_fc, part_fc);
  fc_red_k<<<512, 256, 0, stream>>>(part_fc, bfc1, bfc2, (float*)d_out);
}

// Round 15
// 1299.596 us; speedup vs baseline: 1.0371x; 1.0371x over previous
//
#include <hip/hip_runtime.h>

// PACE DAG-transformer encoder, MI355X bf16-MFMA implementation. Round 15:
// r14 post-mortem: quadrant phases DOUBLE-READ every fragment (48 reads/
// K-tile for 64 MFMA = 0.75/MFMA, worse than r13's 0.5). Re-phase by k-half:
// each phase computes the FULL 128x64 wave tile at fixed kh -> 12 reads for
// 32 MFMA = 0.375/MFMA (25% less LDS traffic than r13, 2x less than r14).
// Two phases per K=64 tile, counted vmcnt(4), 2 barriers per tile.
// Everything else r13-exact.

typedef unsigned short u16;
typedef unsigned int u32;
typedef __attribute__((ext_vector_type(8))) short bf16x8;
typedef __attribute__((ext_vector_type(4))) float f32x4;

#define NB 1024
#define MAXN 32
#define NHID 512
#define NHEAD 8
#define NLAY 6
#define MTOT (NB * MAXN)   // 32768 rows
#define ATT_SCALE 0.125f
#define LN_EPS 1e-5f

__device__ __forceinline__ float bf2f(u16 h) { return __uint_as_float(((u32)h) << 16); }
__device__ __forceinline__ u16 f2bf(float f) {
  u32 u = __float_as_uint(f);
  return (u16)((u + 0x7fffu + ((u >> 16) & 1u)) >> 16);
}

__device__ __forceinline__ void gload16(const void* g, void* l) {
  __builtin_amdgcn_global_load_lds((const __attribute__((address_space(1))) void*)g,
                                   (__attribute__((address_space(3))) void*)l, 16, 0, 0);
}

// XCD-aware remap: all NX n-blocks of one m-panel on one XCD.
__device__ __forceinline__ void xcd_remap(int l, int NX, int& mt, int& nt) {
  int xcd = l & 7;
  int s = l >> 3;
  int mg = s / NX;
  nt = s - mg * NX;
  mt = mg * 8 + xcd;
}

// ---------------------------------------------------------------------------
// DAG reachability mask: per (b,q) a 32-bit "allowed key" mask.
__global__ __launch_bounds__(256) void mask_k(const int* __restrict__ adj, u32* __restrict__ mask) {
  __shared__ u32 r[8][32];
  int tid = threadIdx.x;
  int g = tid >> 5, i = tid & 31;
  int b = blockIdx.x * 8 + g;
  const int* ab = adj + ((long)b * 32 + i) * 32;
  u32 m = 0;
  for (int j = i + 1; j < 32; ++j)
    if (ab[j]) m |= (1u << j);
  r[g][i] = m;
  __syncthreads();
  for (int it = 0; it < 5; ++it) {
    u32 cur = r[g][i];
    u32 acc = cur;
    #pragma unroll
    for (int j = 0; j < 32; ++j)
      if ((cur >> j) & 1u) acc |= r[g][j];
    __syncthreads();
    r[g][i] = acc;
    __syncthreads();
  }
  u32 am = 1u << i;
  #pragma unroll
  for (int k = 0; k < 32; ++k) am |= ((r[g][k] >> i) & 1u) << k;
  mask[b * 32 + i] = am;
}

// ---------------------------------------------------------------------------
// Embedding -> xb (bf16 only).
__global__ __launch_bounds__(256) void embed_k(const int* __restrict__ types,
    const float* __restrict__ Wpos, const float* __restrict__ bpos,
    const float* __restrict__ Wnode, const float* __restrict__ bnode,
    u16* __restrict__ xb) {
  int i = blockIdx.x * 256 + threadIdx.x;
  int row = i >> 7, c = (i & 127) * 4;
  int b = row >> 5, n = row & 31;
  float v[4];
  if (c < 256) {
    int tp = types[b * 32 + n];
    const float* w = &Wnode[tp * 256 + c];
    #pragma unroll
    for (int j = 0; j < 4; ++j) v[j] = fmaxf(w[j] + bnode[c + j], 0.f);
  } else {
    int cc = c - 256;
    const float* w = &Wpos[n * 256 + cc];
    #pragma unroll
    for (int j = 0; j < 4; ++j) v[j] = w[j] + bpos[cc + j];
  }
  ushort4 h; h.x = f2bf(v[0]); h.y = f2bf(v[1]); h.z = f2bf(v[2]); h.w = f2bf(v[3]);
  *(ushort4*)&xb[(long)row * NHID + c] = h;
}

// ---------------------------------------------------------------------------
// Weight transpose + f32->bf16: W[l][k][n] -> Wt[l][n_off+n][k]
__global__ __launch_bounds__(256) void tconv_k(const float* __restrict__ W,
    u16* __restrict__ Wt, int n_off, int n_total) {
  __shared__ float tile[32][33];
  int l = blockIdx.z;
  int k0 = blockIdx.x * 32, n0 = blockIdx.y * 32;
  int tx = threadIdx.x & 31, ty = threadIdx.x >> 5;
  const float* src = W + (size_t)l * NHID * NHID;
  #pragma unroll
  for (int i = 0; i < 4; ++i)
    tile[ty + 8 * i][tx] = src[(size_t)(k0 + ty + 8 * i) * NHID + n0 + tx];
  __syncthreads();
  u16* dst = Wt + (size_t)l * n_total * NHID;
  #pragma unroll
  for (int i = 0; i < 4; ++i)
    dst[(size_t)(n_off + n0 + ty + 8 * i) * NHID + k0 + tx] = f2bf(tile[tx][ty + 8 * i]);
}

// ---------------------------------------------------------------------------
// QKV GEMM, kh-phased schedule: 256x256 tile, BK=64, 8 waves (2M x 4N) of
// 128x64, 128KB LDS. Per K-tile: 2 phases (kh=0,1), each = full wave tile
// (12 ds_read, 32 MFMA); stage A-halves in ph0, B-halves in ph1; counted
// vmcnt(4) + 2 barriers per tile.
__global__ __launch_bounds__(512, 2) void gemm_qkv(
    const u16* __restrict__ A, const u16* __restrict__ Bt,
    const float* __restrict__ bq, const float* __restrict__ bk,
    const float* __restrict__ bv, u16* __restrict__ qk, u16* __restrict__ v) {
  __shared__ u16 Al[2][2][128 * 64];   // [buf][row-half][row*64 + gran*8]  64 KB
  __shared__ u16 Bl[2][2][128 * 64];   // 64 KB
  const int tid = threadIdx.x;
  const int lane = tid & 63;
  const int wave = tid >> 6;
  int mt, nt_;
  xcd_remap(blockIdx.x + gridDim.x * blockIdx.y, gridDim.x, mt, nt_);
  const long m0 = (long)mt * 256;
  const int n0 = nt_ * 256;
  const int wr = wave >> 2;            // 0..1 : 128-row half
  const int wcn = wave & 3;            // 0..3 : 64-col quarter
  const int fr = lane & 15, kq = lane >> 4;
  const int sr = tid >> 3, sp = tid & 7;    // stage row (0..63), granule pos
  const int sgg = sp ^ (sr & 7);            // pre-swizzled global granule
  f32x4 acc[8][4] = {};

  // stage one half-tile (128 rows x 64 k): hsel 0,1 = A halves; 2,3 = B halves
  auto stageH = [&](int kt, int hsel) {
    int buf = kt & 1;
    int kof = kt * 64 + sgg * 8;
    if (hsel < 2) {
      const u16* src = A + (m0 + hsel * 128 + sr) * 512L + kof;
      u16* dst = &Al[buf][hsel][sr * 64 + sp * 8];
      gload16(src, dst);
      gload16(src + 64 * 512L, dst + 64 * 64);
    } else {
      const u16* src = Bt + (long)(n0 + (hsel - 2) * 128 + sr) * 512 + kof;
      u16* dst = &Bl[buf][hsel - 2][sr * 64 + sp * 8];
      gload16(src, dst);
      gload16(src + 64 * 512L, dst + 64 * 64);
    }
  };
  stageH(0, 0); stageH(0, 1); stageH(0, 2); stageH(0, 3);   // 8 gloads

  #pragma unroll 1
  for (int kt = 0; kt < 8; ++kt) {
    const int buf = kt & 1;
    const u16* Ah = &Al[buf][wr][0];
    const u16* B0 = &Bl[buf][0][0];
    const u16* B1 = &Bl[buf][1][0];
    // prefetch A-halves of kt+1, then wait for ALL of kt's 8 loads.
    if (kt < 7) {
      stageH(kt + 1, 0); stageH(kt + 1, 1);
      asm volatile("s_waitcnt vmcnt(4)" ::: "memory");
    } else {
      asm volatile("s_waitcnt vmcnt(0)" ::: "memory");
    }
    __builtin_amdgcn_s_barrier();        // kt's tile visible to all waves
    #pragma unroll
    for (int kh = 0; kh < 2; ++kh) {
      if (kh == 1 && kt < 7) { stageH(kt + 1, 2); stageH(kt + 1, 3); }
      const int p = (kh * 4 + kq) ^ (fr & 7);   // swizzled granule (row&7 == fr&7)
      bf16x8 af[8], bfv[4];
      #pragma unroll
      for (int m2 = 0; m2 < 8; ++m2)
        af[m2] = *(const bf16x8*)&Ah[(m2 * 16 + fr) * 64 + p * 8];
      #pragma unroll
      for (int n2 = 0; n2 < 4; ++n2) {
        int c = wcn * 64 + n2 * 16 + fr;
        const u16* Bh = (c < 128) ? B0 : B1;
        bfv[n2] = *(const bf16x8*)&Bh[(c & 127) * 64 + p * 8];
      }
      __builtin_amdgcn_s_setprio(1);
      #pragma unroll
      for (int m2 = 0; m2 < 8; ++m2)
        #pragma unroll
        for (int n2 = 0; n2 < 4; ++n2)
          acc[m2][n2] = __builtin_amdgcn_mfma_f32_16x16x32_bf16(bfv[n2], af[m2], acc[m2][n2], 0, 0, 0);
      __builtin_amdgcn_s_setprio(0);
    }
    __builtin_amdgcn_s_barrier();        // buf reads done before kt+2 overwrites
  }

  #pragma unroll
  for (int mi = 0; mi < 8; ++mi) {
    long r = m0 + wr * 128 + mi * 16 + fr;
    #pragma unroll
    for (int ni = 0; ni < 4; ++ni) {
      int n = n0 + wcn * 64 + ni * 16 + kq * 4;
      const float* bp = (n < 512) ? bq : ((n < 1024) ? bk : bv);
      float4 bvv = *(const float4*)&bp[n & 511];
      ushort4 st;
      st.x = f2bf(acc[mi][ni][0] + bvv.x);
      st.y = f2bf(acc[mi][ni][1] + bvv.y);
      st.z = f2bf(acc[mi][ni][2] + bvv.z);
      st.w = f2bf(acc[mi][ni][3] + bvv.w);
      if (n < 1024) *(ushort4*)&qk[r * 1024 + n] = st;
      else          *(ushort4*)&v[r * 512 + (n - 1024)] = st;
    }
  }
}

// ---------------------------------------------------------------------------
// W1 GEMM (bias+relu): 128x128 tile, 2-slot, 4 blocks/CU, setprio. (r13-exact)
__global__ __launch_bounds__(256, 4) void gemm_relu(
    const u16* __restrict__ A, const u16* __restrict__ Bt,
    const float* __restrict__ bias0, u16* __restrict__ Cout) {
  __shared__ u16 As[2][128 * 32];
  __shared__ u16 Bs[2][128 * 32];
  const int tid = threadIdx.x;
  const int wave = tid >> 6, lane = tid & 63;
  int mt, nt_;
  xcd_remap(blockIdx.x + gridDim.x * blockIdx.y, gridDim.x, mt, nt_);
  const long m0 = (long)mt * 128;
  const int n0 = nt_ * 128;
  const int wr = wave >> 1, wc = wave & 1;
  const int srow = lane >> 2;
  const int sg = (lane & 3) ^ ((srow >> 1) & 3);
  const int fr = lane & 15;
  const int kq = lane >> 4;
  f32x4 acc[4][4] = {};

  auto stage = [&](int buf, int k0) {
    #pragma unroll
    for (int i = 0; i < 2; ++i) {
      int c = 2 * wave + i;
      gload16(A + (m0 + 16 * c + srow) * 512L + k0 + sg * 8, &As[buf][c * 512]);
      gload16(Bt + (long)(n0 + 16 * c + srow) * 512 + k0 + sg * 8, &Bs[buf][c * 512]);
    }
  };
  stage(0, 0);
  const int kqx = (kq ^ ((fr >> 1) & 3)) * 8;
  #pragma unroll 1
  for (int t = 0; t < 16; ++t) {
    asm volatile("s_waitcnt vmcnt(0)" ::: "memory");
    __builtin_amdgcn_s_barrier();
    if (t + 1 < 16) stage((t + 1) & 1, (t + 1) * 32);
    const u16* Asl = As[t & 1];
    const u16* Bsl = Bs[t & 1];
    __builtin_amdgcn_s_setprio(1);
    bf16x8 af[4], bfv[4];
    #pragma unroll
    for (int mi = 0; mi < 4; ++mi)
      af[mi] = *(const bf16x8*)&Asl[(wr * 64 + mi * 16 + fr) * 32 + kqx];
    #pragma unroll
    for (int ni = 0; ni < 4; ++ni)
      bfv[ni] = *(const bf16x8*)&Bsl[(wc * 64 + ni * 16 + fr) * 32 + kqx];
    #pragma unroll
    for (int mi = 0; mi < 4; ++mi)
      #pragma unroll
      for (int ni = 0; ni < 4; ++ni)
        acc[mi][ni] = __builtin_amdgcn_mfma_f32_16x16x32_bf16(bfv[ni], af[mi], acc[mi][ni], 0, 0, 0);
    __builtin_amdgcn_s_setprio(0);
  }

  #pragma unroll
  for (int mi = 0; mi < 4; ++mi) {
    long r = m0 + wr * 64 + mi * 16 + fr;
    #pragma unroll
    for (int ni = 0; ni < 4; ++ni) {
      int n = n0 + wc * 64 + ni * 16 + kq * 4;
      float4 bvv = *(const float4*)&bias0[n];
      ushort4 st;
      st.x = f2bf(fmaxf(acc[mi][ni][0] + bvv.x, 0.f));
      st.y = f2bf(fmaxf(acc[mi][ni][1] + bvv.y, 0.f));
      st.z = f2bf(fmaxf(acc[mi][ni][2] + bvv.z, 0.f));
      st.w = f2bf(fmaxf(acc[mi][ni][3] + bvv.w, 0.f));
      *(ushort4*)&Cout[r * 512 + n] = st;
    }
  }
}

// ---------------------------------------------------------------------------
// GEMM + residual + LayerNorm: 128x512 block, 8 waves of 64x128, 2-slot 80KB,
// (512,2). (r13-exact)
__global__ __launch_bounds__(512, 2) void gemm_ln(
    const u16* __restrict__ A, const u16* __restrict__ Bt,
    const float* __restrict__ bias0, const float* __restrict__ g,
    const float* __restrict__ b, u16* __restrict__ xb) {
  __shared__ u16 As[2][128 * 32];
  __shared__ u16 Bs[2][512 * 32];
  const int tid = threadIdx.x;
  const int wave = tid >> 6, lane = tid & 63;
  const long m0 = (long)blockIdx.x * 128;
  const int wr = wave >> 2, wc = wave & 3;
  const int srow = lane >> 2;
  const int sg = (lane & 3) ^ ((srow >> 1) & 3);
  const int fr = lane & 15;
  const int kq = lane >> 4;
  f32x4 acc[4][8] = {};

  auto stage = [&](int buf, int k0) {
    gload16(A + (m0 + 16 * wave + srow) * 512L + k0 + sg * 8, &As[buf][wave * 512]);
    #pragma unroll
    for (int i = 0; i < 4; ++i) {
      int c = 4 * wave + i;
      gload16(Bt + (long)(16 * c + srow) * 512 + k0 + sg * 8, &Bs[buf][c * 512]);
    }
  };
  stage(0, 0);
  const int kqx = (kq ^ ((fr >> 1) & 3)) * 8;
  #pragma unroll 1
  for (int t = 0; t < 16; ++t) {
    asm volatile("s_waitcnt vmcnt(0)" ::: "memory");
    __builtin_amdgcn_s_barrier();
    if (t + 1 < 16) stage((t + 1) & 1, (t + 1) * 32);
    const u16* Asl = As[t & 1];
    const u16* Bsl = Bs[t & 1];
    __builtin_amdgcn_s_setprio(1);
    bf16x8 af[4], bfv[8];
    #pragma unroll
    for (int mi = 0; mi < 4; ++mi)
      af[mi] = *(const bf16x8*)&Asl[(wr * 64 + mi * 16 + fr) * 32 + kqx];
    #pragma unroll
    for (int ni = 0; ni < 8; ++ni)
      bfv[ni] = *(const bf16x8*)&Bsl[(wc * 128 + ni * 16 + fr) * 32 + kqx];
    #pragma unroll
    for (int mi = 0; mi < 4; ++mi)
      #pragma unroll
      for (int ni = 0; ni < 8; ++ni)
        acc[mi][ni] = __builtin_amdgcn_mfma_f32_16x16x32_bf16(bfv[ni], af[mi], acc[mi][ni], 0, 0, 0);
    __builtin_amdgcn_s_setprio(0);
  }

  float s[4], sq[4];
  #pragma unroll
  for (int mi = 0; mi < 4; ++mi) {
    long r = m0 + wr * 64 + mi * 16 + fr;
    float ss = 0.f, qq = 0.f;
    #pragma unroll
    for (int ni = 0; ni < 8; ++ni) {
      int n = wc * 128 + ni * 16 + kq * 4;
      float4 bvv = *(const float4*)&bias0[n];
      ushort4 rv = *(const ushort4*)&xb[r * 512 + n];
      float y0 = acc[mi][ni][0] + bvv.x + bf2f(rv.x);
      float y1 = acc[mi][ni][1] + bvv.y + bf2f(rv.y);
      float y2 = acc[mi][ni][2] + bvv.z + bf2f(rv.z);
      float y3 = acc[mi][ni][3] + bvv.w + bf2f(rv.w);
      acc[mi][ni][0] = y0; acc[mi][ni][1] = y1;
      acc[mi][ni][2] = y2; acc[mi][ni][3] = y3;
      ss += y0 + y1 + y2 + y3;
      qq += y0 * y0 + y1 * y1 + y2 * y2 + y3 * y3;
    }
    s[mi] = ss; sq[mi] = qq;
  }
  #pragma unroll
  for (int mi = 0; mi < 4; ++mi) {
    s[mi] += __shfl_xor(s[mi], 16);  sq[mi] += __shfl_xor(sq[mi], 16);
    s[mi] += __shfl_xor(s[mi], 32);  sq[mi] += __shfl_xor(sq[mi], 32);
  }
  __syncthreads();
  float* red = (float*)&As[0][0];
  if (lane < 16) {
    #pragma unroll
    for (int mi = 0; mi < 4; ++mi) {
      int idx = ((wr * 64 + mi * 16 + fr) * 4 + wc) * 2;
      red[idx] = s[mi];
      red[idx + 1] = sq[mi];
    }
  }
  __syncthreads();
  #pragma unroll
  for (int mi = 0; mi < 4; ++mi) {
    int rl = wr * 64 + mi * 16 + fr;
    float S = red[(rl * 4 + 0) * 2] + red[(rl * 4 + 1) * 2] + red[(rl * 4 + 2) * 2] + red[(rl * 4 + 3) * 2];
    float Q = red[(rl * 4 + 0) * 2 + 1] + red[(rl * 4 + 1) * 2 + 1] + red[(rl * 4 + 2) * 2 + 1] + red[(rl * 4 + 3) * 2 + 1];
    float mean = S * (1.f / 512.f);
    float inv = rsqrtf(Q * (1.f / 512.f) - mean * mean + LN_EPS);
    long r = m0 + rl;
    #pragma unroll
    for (int ni = 0; ni < 8; ++ni) {
      int n = wc * 128 + ni * 16 + kq * 4;
      float4 g4 = *(const float4*)&g[n];
      float4 b4 = *(const float4*)&b[n];
      ushort4 st;
      st.x = f2bf((acc[mi][ni][0] - mean) * inv * g4.x + b4.x);
      st.y = f2bf((acc[mi][ni][1] - mean) * inv * g4.y + b4.y);
      st.z = f2bf((acc[mi][ni][2] - mean) * inv * g4.z + b4.z);
      st.w = f2bf((acc[mi][ni][3] - mean) * inv * g4.w + b4.w);
      *(ushort4*)&xb[r * 512 + n] = st;
    }
  }
}

// ---------------------------------------------------------------------------
// MFMA attention: 1 wave per (b,head), 4 waves/block, no barriers. (r13-exact)
__global__ __launch_bounds__(256) void attn_k(const u16* __restrict__ qk,
    const u16* __restrict__ vfull, const u32* __restrict__ mask, u16* __restrict__ o) {
  __shared__ u16 vs_[4][64][40];
  __shared__ u16 p_lds[4][32][40];
  int tid = threadIdx.x;
  int w = tid >> 6, lane = tid & 63;
  int idx = blockIdx.x * 4 + w;
  int b = idx >> 3, h = idx & 7;
  const u16* qbase = qk + (long)b * 32 * 1024 + h * 64;
  const u16* kbase = qbase + 512;
  int g = lane >> 4, r = lane & 15;

  int node = lane >> 1, dh = lane & 1;
  const u16* vsrc = vfull + ((long)b * 32 + node) * 512 + h * 64 + dh * 32;
  bf16x8 vr[4];
  #pragma unroll
  for (int i = 0; i < 4; ++i) vr[i] = *(const bf16x8*)(vsrc + i * 8);

  f32x4 s[2][2] = {};
  #pragma unroll
  for (int ks = 0; ks < 2; ++ks) {
    bf16x8 kf[2], qf[2];
    #pragma unroll
    for (int mi = 0; mi < 2; ++mi)
      kf[mi] = *(const bf16x8*)(kbase + (long)(mi * 16 + r) * 1024 + ks * 32 + g * 8);
    #pragma unroll
    for (int nj = 0; nj < 2; ++nj)
      qf[nj] = *(const bf16x8*)(qbase + (long)(nj * 16 + r) * 1024 + ks * 32 + g * 8);
    #pragma unroll
    for (int mi = 0; mi < 2; ++mi)
      #pragma unroll
      for (int nj = 0; nj < 2; ++nj)
        s[mi][nj] = __builtin_amdgcn_mfma_f32_16x16x32_bf16(kf[mi], qf[nj], s[mi][nj], 0, 0, 0);
  }

  #pragma unroll
  for (int i = 0; i < 4; ++i)
    #pragma unroll
    for (int t = 0; t < 8; ++t)
      vs_[w][dh * 32 + i * 8 + t][node] = (u16)vr[i][t];

  #pragma unroll
  for (int nj = 0; nj < 2; ++nj) {
    int q = nj * 16 + r;
    u32 mk = mask[b * 32 + q];
    float vv[8];
    float mx = -1e30f;
    #pragma unroll
    for (int mi = 0; mi < 2; ++mi)
      #pragma unroll
      for (int j = 0; j < 4; ++j) {
        int k = mi * 16 + g * 4 + j;
        float val = ((mk >> k) & 1u) ? s[mi][nj][j] * ATT_SCALE : -1e30f;
        vv[mi * 4 + j] = val;
        mx = fmaxf(mx, val);
      }
    mx = fmaxf(mx, __shfl_xor(mx, 16));
    mx = fmaxf(mx, __shfl_xor(mx, 32));
    float sum = 0.f;
    #pragma unroll
    for (int i = 0; i < 8; ++i) { vv[i] = __expf(vv[i] - mx); sum += vv[i]; }
    sum += __shfl_xor(sum, 16);
    sum += __shfl_xor(sum, 32);
    float inv = 1.f / sum;
    #pragma unroll
    for (int mi = 0; mi < 2; ++mi) {
      ushort4 pk;
      pk.x = f2bf(vv[mi * 4 + 0] * inv);
      pk.y = f2bf(vv[mi * 4 + 1] * inv);
      pk.z = f2bf(vv[mi * 4 + 2] * inv);
      pk.w = f2bf(vv[mi * 4 + 3] * inv);
      *(ushort4*)&p_lds[w][q][mi * 16 + g * 4] = pk;
    }
  }

  bf16x8 pa[2];
  #pragma unroll
  for (int mi = 0; mi < 2; ++mi)
    pa[mi] = *(const bf16x8*)&p_lds[w][mi * 16 + r][g * 8];
  f32x4 oacc[2][4] = {};
  #pragma unroll
  for (int nd = 0; nd < 4; ++nd) {
    bf16x8 vf = *(const bf16x8*)&vs_[w][nd * 16 + r][g * 8];
    #pragma unroll
    for (int mi = 0; mi < 2; ++mi)
      oacc[mi][nd] = __builtin_amdgcn_mfma_f32_16x16x32_bf16(pa[mi], vf, oacc[mi][nd], 0, 0, 0);
  }
  #pragma unroll
  for (int mi = 0; mi < 2; ++mi)
    #pragma unroll
    for (int j = 0; j < 4; ++j) {
      int q = mi * 16 + g * 4 + j;
      u16* og = o + ((long)b * 32 + q) * NHID + h * 64;
      #pragma unroll
      for (int nd = 0; nd < 4; ++nd)
        og[nd * 16 + r] = f2bf(oacc[mi][nd][j]);
    }
}

// ---------------------------------------------------------------------------
// Final FC weight transpose: W[16384][64] f32 -> Wt[sel*64 + n][16384] bf16.
__global__ __launch_bounds__(256) void fcT_k(const float* __restrict__ W1,
    const float* __restrict__ W2, u16* __restrict__ Wt) {
  __shared__ float t[64][65];
  int sel = blockIdx.y;
  const float* W = sel ? W2 : W1;
  int k0 = blockIdx.x * 64;
  int tx = threadIdx.x & 63, ty = threadIdx.x >> 6;
  #pragma unroll
  for (int i = 0; i < 16; ++i)
    t[ty + 4 * i][tx] = W[(long)(k0 + ty + 4 * i) * 64 + tx];
  __syncthreads();
  #pragma unroll
  for (int i = 0; i < 16; ++i)
    Wt[(long)(sel * 64 + ty + 4 * i) * 16384 + k0 + tx] = f2bf(t[tx][ty + 4 * i]);
}

// ---------------------------------------------------------------------------
// Final FC GEMM (2-slot, swapped-operand), K-split: part[ks][1024][128].
__global__ __launch_bounds__(256, 4) void gemm_fc(const u16* __restrict__ A,
    const u16* __restrict__ Bt, float* __restrict__ part) {
  __shared__ u16 As[2][128 * 32];
  __shared__ u16 Bs[2][128 * 32];
  const int tid = threadIdx.x;
  const int wave = tid >> 6, lane = tid & 63;
  const int ks = blockIdx.x;
  const long m0 = (long)blockIdx.y * 128;
  const int kbase = ks * 512;
  const int wr = wave >> 1, wc = wave & 1;
  const int srow = lane >> 2;
  const int sg = (lane & 3) ^ ((srow >> 1) & 3);
  const int fr = lane & 15;
  const int kq = lane >> 4;
  f32x4 acc[4][4] = {};
  auto stage = [&](int buf, int k0) {
    #pragma unroll
    for (int i = 0; i < 2; ++i) {
      int c = 2 * wave + i;
      gload16(A + (m0 + 16 * c + srow) * 16384L + kbase + k0 + sg * 8, &As[buf][c * 512]);
      gload16(Bt + (long)(16 * c + srow) * 16384L + kbase + k0 + sg * 8, &Bs[buf][c * 512]);
    }
  };
  stage(0, 0);
  const int kqx = (kq ^ ((fr >> 1) & 3)) * 8;
  #pragma unroll 1
  for (int t = 0; t < 16; ++t) {
    asm volatile("s_waitcnt vmcnt(0)" ::: "memory");
    __builtin_amdgcn_s_barrier();
    if (t + 1 < 16) stage((t + 1) & 1, (t + 1) * 32);
    const u16* Asl = As[t & 1];
    const u16* Bsl = Bs[t & 1];
    __builtin_amdgcn_s_setprio(1);
    bf16x8 af[4], bfv[4];
    #pragma unroll
    for (int mi = 0; mi < 4; ++mi)
      af[mi] = *(const bf16x8*)&Asl[(wr * 64 + mi * 16 + fr) * 32 + kqx];
    #pragma unroll
    for (int ni = 0; ni < 4; ++ni)
      bfv[ni] = *(const bf16x8*)&Bsl[(wc * 64 + ni * 16 + fr) * 32 + kqx];
    #pragma unroll
    for (int mi = 0; mi < 4; ++mi)
      #pragma unroll
      for (int ni = 0; ni < 4; ++ni)
        acc[mi][ni] = __builtin_amdgcn_mfma_f32_16x16x32_bf16(bfv[ni], af[mi], acc[mi][ni], 0, 0, 0);
    __builtin_amdgcn_s_setprio(0);
  }
  #pragma unroll
  for (int mi = 0; mi < 4; ++mi) {
    long rr = m0 + wr * 64 + mi * 16 + fr;
    #pragma unroll
    for (int ni = 0; ni < 4; ++ni) {
      int n = wc * 64 + ni * 16 + kq * 4;
      *(float4*)&part[((long)ks * 1024 + rr) * 128 + n] =
          make_float4(acc[mi][ni][0], acc[mi][ni][1], acc[mi][ni][2], acc[mi][ni][3]);
    }
  }
}

__global__ __launch_bounds__(256) void fc_red_k(const float* __restrict__ part,
    const float* __restrict__ bfc1, const float* __restrict__ bfc2,
    float* __restrict__ out) {
  int idx = blockIdx.x * 256 + threadIdx.x;
  int sel = idx >> 16;
  int rem = idx & 65535;
  int b = rem >> 6, z = rem & 63;
  float v = sel ? bfc2[z] : bfc1[z];
  #pragma unroll
  for (int ks = 0; ks < 32; ++ks)
    v += part[((long)ks * 1024 + b) * 128 + sel * 64 + z];
  out[idx] = v;
}

// ---------------------------------------------------------------------------
extern "C" void kernel_launch(void* const* d_in, const int* in_sizes, int n_in,
                              void* d_out, int out_size, void* d_ws, size_t ws_size,
                              hipStream_t stream) {
  const int* node_types = (const int*)d_in[0];
  const int* adj_bits = (const int*)d_in[1];
  const float* Wpos = (const float*)d_in[2];
  const float* bpos = (const float*)d_in[3];
  const float* Wnode = (const float*)d_in[4];
  const float* bnode = (const float*)d_in[5];
  const float* eWq = (const float*)d_in[6];
  const float* eWk = (const float*)d_in[7];
  const float* eWv = (const float*)d_in[8];
  const float* eWo = (const float*)d_in[9];
  const float* eW1 = (const float*)d_in[10];
  const float* eW2 = (const float*)d_in[11];
  const float* ebq = (const float*)d_in[12];
  const float* ebk = (const float*)d_in[13];
  const float* ebv = (const float*)d_in[14];
  const float* ebo = (const float*)d_in[15];
  const float* eb1 = (const float*)d_in[16];
  const float* eb2 = (const float*)d_in[17];
  const float* ln1g = (const float*)d_in[18];
  const float* ln1b = (const float*)d_in[19];
  const float* ln2g = (const float*)d_in[20];
  const float* ln2b = (const float*)d_in[21];
  const float* Wfc1 = (const float*)d_in[22];
  const float* bfc1 = (const float*)d_in[23];
  const float* Wfc2 = (const float*)d_in[24];
  const float* bfc2 = (const float*)d_in[25];

  char* ws = (char*)d_ws;
  size_t off = 0;
  auto carve = [&](size_t bytes) {
    void* p = ws + off;
    off += (bytes + 255) & ~(size_t)255;
    return p;
  };
  u16* Wqkv_t = (u16*)carve((size_t)NLAY * 1536 * 512 * 2);
  u16* Wo_t = (u16*)carve((size_t)NLAY * 512 * 512 * 2);
  u16* W1_t = (u16*)carve((size_t)NLAY * 512 * 512 * 2);
  u16* W2_t = (u16*)carve((size_t)NLAY * 512 * 512 * 2);
  u16* xb = (u16*)carve((size_t)MTOT * NHID * 2);       // 32 MB: layer state
  u16* qk = (u16*)carve((size_t)MTOT * 1024 * 2);       // 64 MB: Q,K / Wt_fc
  u16* vbuf = (u16*)carve((size_t)MTOT * NHID * 2);     // 32 MB: V packed
  u16* obuf = (u16*)carve((size_t)MTOT * NHID * 2);     // 32 MB: attn out / hbuf / part
  u32* maskb = (u32*)carve((size_t)NB * MAXN * 4);
  u16* hbuf = obuf;               // MLP hidden
  u16* Wt_fc = qk;                // FC-time alias: 4 MB
  float* part_fc = (float*)obuf;  // FC-time alias: 16.8 MB

  // --- prep ---
  mask_k<<<NB / 8, 256, 0, stream>>>(adj_bits, maskb);
  embed_k<<<(MTOT * 128) / 256, 256, 0, stream>>>(node_types, Wpos, bpos, Wnode, bnode, xb);
  dim3 tg(16, 16, NLAY);
  tconv_k<<<tg, 256, 0, stream>>>(eWq, Wqkv_t, 0, 1536);
  tconv_k<<<tg, 256, 0, stream>>>(eWk, Wqkv_t, 512, 1536);
  tconv_k<<<tg, 256, 0, stream>>>(eWv, Wqkv_t, 1024, 1536);
  tconv_k<<<tg, 256, 0, stream>>>(eWo, Wo_t, 0, 512);
  tconv_k<<<tg, 256, 0, stream>>>(eW1, W1_t, 0, 512);
  tconv_k<<<tg, 256, 0, stream>>>(eW2, W2_t, 0, 512);

  // --- encoder layers ---
  for (int l = 0; l < NLAY; ++l) {
    size_t lw = (size_t)l * 512 * 512;
    gemm_qkv<<<dim3(6, MTOT / 256), 512, 0, stream>>>(
        xb, Wqkv_t + (size_t)l * 1536 * 512,
        ebq + l * 512, ebk + l * 512, ebv + l * 512, qk, vbuf);
    attn_k<<<NB * NHEAD / 4, 256, 0, stream>>>(qk, vbuf, maskb, obuf);
    gemm_ln<<<MTOT / 128, 512, 0, stream>>>(
        obuf, Wo_t + lw, ebo + l * 512, ln1g + l * 512, ln1b + l * 512, xb);
    gemm_relu<<<dim3(4, MTOT / 128), 256, 0, stream>>>(
        xb, W1_t + lw, eb1 + l * 512, hbuf);
    gemm_ln<<<MTOT / 128, 512, 0, stream>>>(
        hbuf, W2_t + lw, eb2 + l * 512, ln2g + l * 512, ln2b + l * 512, xb);
  }

  // --- final FC: transpose weights (dead qk region), K-split MFMA, reduce ---
  fcT_k<<<dim3(256, 2), 256, 0, stream>>>(Wfc1, Wfc2, Wt_fc);
  gemm_fc<<<dim3(32, 8), 256, 0, stream>>>(xb, Wt_fc, part_fc);
  fc_red_k<<<512, 256, 0, stream>>>(part_fc, bfc1, bfc2, (float*)d_out);
}